// Round 6
// baseline (305.186 us; speedup 1.0000x reference)
//
#include <hip/hip_runtime.h>
#include <hip/hip_bf16.h>

// DTWLoss: out[b] = softDTW(sqdist(x,y)) - 0.5*(softDTW(sqdist(x,x)) + softDTW(sqdist(y,y)))
// B=64, N=M=512, F=256, gamma=0.1, BIG=1e8. Output: 64 fp32.
//
// Phase 1: convert x,y to bf16 + fp32 row norms (HBM BW-bound, ~33us floor).
// Phase 2: 192 batched MFMA GEMMs, 128x128 tile, LDS dbuf chunk K=32.
//          LDA=34 (17-bank odd stride: conflict-free b128 LDS reads).
//          z = 3*b + p so all 48 blocks of a batch share L2-resident inputs.
//          Epilogue transposes through LDS -> 256B-contiguous column-segment
//          stores (kills the 155MB->96MB write amplification of scattered 8B).
// Phase 3: barrier-free wavefront DTW (hardmin; |softmin-min|<=gamma*ln3/cell,
//          <=112 total vs 5242.88 threshold). ONE WAVE per matrix, lane t owns
//          rows [8t,8t+8). Depth-2 group-8 prefetch: 16 independent 16B loads
//          in flight, consumed 2 groups (~1500cyc) later >> HBM latency.

#define SDTW_BIG   1e8f
#define LDA 34      // LDS row stride in shorts (32 + 2 pad -> 17 banks, odd)
#define TSTRIDE 132 // transpose-buffer column stride in shorts

typedef __attribute__((ext_vector_type(8))) short short8;   // 8 bf16
typedef __attribute__((ext_vector_type(4))) float floatx4;  // mfma acc

__device__ __forceinline__ unsigned short f2bf(float f) {
    __hip_bfloat16 h = __float2bfloat16(f);
    return *reinterpret_cast<unsigned short*>(&h);
}
__device__ __forceinline__ float bf2f_lo(unsigned int u) {
    return __uint_as_float(u << 16);
}
__device__ __forceinline__ float bf2f_hi(unsigned int u) {
    return __uint_as_float(u & 0xFFFF0000u);
}

// ---- Phase 1: fp32 -> bf16 + row sum-of-squares (fp32) --------------------
__global__ __launch_bounds__(256) void convert_norm_kernel(
    const float* __restrict__ x, const float* __restrict__ y,
    unsigned short* __restrict__ xb, unsigned short* __restrict__ yb,
    float* __restrict__ nx, float* __restrict__ ny) {
    const float* src = blockIdx.y ? y : x;
    unsigned short* dst = blockIdx.y ? yb : xb;
    float* nrm = blockIdx.y ? ny : nx;
    const int wave = threadIdx.x >> 6;
    const int lane = threadIdx.x & 63;
    const int row  = blockIdx.x * 4 + wave;          // 0..32767
    const float4 v = reinterpret_cast<const float4*>(src + (size_t)row * 256)[lane];
    float ss = v.x * v.x + v.y * v.y + v.z * v.z + v.w * v.w;
    ushort4 u;
    u.x = f2bf(v.x); u.y = f2bf(v.y); u.z = f2bf(v.z); u.w = f2bf(v.w);
    reinterpret_cast<ushort4*>(dst + (size_t)row * 256)[lane] = u;
    #pragma unroll
    for (int o = 32; o; o >>= 1) ss += __shfl_down(ss, o);
    if (lane == 0) nrm[row] = ss;
}

// ---- Phase 2: D = nA[i] + nB[j] - 2*A.B^T, bf16 col-major -----------------
// grid (4, 4, 192) x 256 threads. z = 3*b + p (batch-major for L2 locality).
__global__ __launch_bounds__(256) void gemm_lds_kernel(
    const unsigned short* __restrict__ xb, const unsigned short* __restrict__ yb,
    const float* __restrict__ nx, const float* __restrict__ ny,
    unsigned short* __restrict__ Dws) {
    // Ab/Bb: 2 bufs x 128 rows x LDA shorts each = 34816 B total.
    // T (epilogue transpose, 128 cols x TSTRIDE shorts = 33792 B) aliases them.
    __shared__ short smem[4 * 128 * LDA];
    short* Ab[2] = { smem, smem + 128 * LDA };
    short* Bb[2] = { smem + 2 * 128 * LDA, smem + 3 * 128 * LDA };
    short* T = smem;

    const int z = blockIdx.z;            // 3*b + p
    const int b = z / 3;
    const int p = z - 3 * b;
    const unsigned short* A  = (p == 2) ? yb : xb;
    const unsigned short* Bm = (p == 1) ? xb : yb;
    const float* nA = (p == 2) ? ny : nx;
    const float* nB = (p == 1) ? nx : ny;
    A  += (size_t)b * (512 * 256);
    Bm += (size_t)b * (512 * 256);
    nA += b * 512;
    nB += b * 512;
    unsigned short* Dmat = Dws + (size_t)z * (512 * 512);

    const int tid  = threadIdx.x;
    const int wave = tid >> 6;
    const int lane = tid & 63;
    const int quad = lane >> 4;
    const int l16  = lane & 15;
    const int wr = wave >> 1, wc = wave & 1;
    const int i0base = blockIdx.x * 128;
    const int j0base = blockIdx.y * 128;

    // Staging: thread tid handles 16B quarters (row=tid>>2, q=tid&3) of rows
    // [0,64) and [64,128) for both A and B tiles.
    const int srow = tid >> 2;
    const int sq   = tid & 3;
    const short8* gA0 = reinterpret_cast<const short8*>(A  + (size_t)(i0base + srow)      * 256 + sq * 8);
    const short8* gA1 = reinterpret_cast<const short8*>(A  + (size_t)(i0base + srow + 64) * 256 + sq * 8);
    const short8* gB0 = reinterpret_cast<const short8*>(Bm + (size_t)(j0base + srow)      * 256 + sq * 8);
    const short8* gB1 = reinterpret_cast<const short8*>(Bm + (size_t)(j0base + srow + 64) * 256 + sq * 8);
    const int lO0 = srow * LDA + sq * 8;
    const int lO1 = (srow + 64) * LDA + sq * 8;

    // Preload chunk 0 -> buf 0.
    {
        short8 ra0 = gA0[0], ra1 = gA1[0], rb0 = gB0[0], rb1 = gB1[0];
        *reinterpret_cast<short8*>(&Ab[0][lO0]) = ra0;
        *reinterpret_cast<short8*>(&Ab[0][lO1]) = ra1;
        *reinterpret_cast<short8*>(&Bb[0][lO0]) = rb0;
        *reinterpret_cast<short8*>(&Bb[0][lO1]) = rb1;
    }
    __syncthreads();

    floatx4 acc[4][4];
    #pragma unroll
    for (int mt = 0; mt < 4; ++mt)
        #pragma unroll
        for (int nt = 0; nt < 4; ++nt) acc[mt][nt] = (floatx4){0.f, 0.f, 0.f, 0.f};

    #pragma unroll
    for (int c = 0; c < 8; ++c) {
        const int cb = c & 1;
        short8 na0, na1, nb0, nb1;
        if (c < 7) {                      // issue next chunk's global loads
            na0 = gA0[(c + 1) * 4]; na1 = gA1[(c + 1) * 4];
            nb0 = gB0[(c + 1) * 4]; nb1 = gB1[(c + 1) * 4];
        }
        short8 af[4], bfr[4];
        #pragma unroll
        for (int mt = 0; mt < 4; ++mt)
            af[mt] = *reinterpret_cast<const short8*>(&Ab[cb][(wr * 64 + mt * 16 + l16) * LDA + quad * 8]);
        #pragma unroll
        for (int nt = 0; nt < 4; ++nt)
            bfr[nt] = *reinterpret_cast<const short8*>(&Bb[cb][(wc * 64 + nt * 16 + l16) * LDA + quad * 8]);
        #pragma unroll
        for (int mt = 0; mt < 4; ++mt)
            #pragma unroll
            for (int nt = 0; nt < 4; ++nt)
                acc[mt][nt] = __builtin_amdgcn_mfma_f32_16x16x32_bf16(af[mt], bfr[nt], acc[mt][nt], 0, 0, 0);
        if (c < 7) {                      // stage next chunk after MFMA burst
            *reinterpret_cast<short8*>(&Ab[1 - cb][lO0]) = na0;
            *reinterpret_cast<short8*>(&Ab[1 - cb][lO1]) = na1;
            *reinterpret_cast<short8*>(&Bb[1 - cb][lO0]) = nb0;
            *reinterpret_cast<short8*>(&Bb[1 - cb][lO1]) = nb1;
            __syncthreads();
        }
    }

    // Epilogue: fragments (C/D layout col=lane&15, row=quad*4+reg) -> LDS
    // transpose tile -> fully-coalesced 256B column-segment stores.
    __syncthreads();                      // all LDS reads done; reuse as T
    #pragma unroll
    for (int mt = 0; mt < 4; ++mt) {
        const int il = wr * 64 + mt * 16 + quad * 4;
        const float4 nv = *reinterpret_cast<const float4*>(nA + i0base + il);
        #pragma unroll
        for (int nt = 0; nt < 4; ++nt) {
            const int jl = wc * 64 + nt * 16 + l16;
            const float y2 = nB[j0base + jl];
            ushort4 pk;
            pk.x = f2bf(nv.x + y2 - 2.0f * acc[mt][nt][0]);
            pk.y = f2bf(nv.y + y2 - 2.0f * acc[mt][nt][1]);
            pk.z = f2bf(nv.z + y2 - 2.0f * acc[mt][nt][2]);
            pk.w = f2bf(nv.w + y2 - 2.0f * acc[mt][nt][3]);
            *reinterpret_cast<ushort4*>(&T[jl * TSTRIDE + il]) = pk;
        }
    }
    __syncthreads();
    // Readout: 16 threads per column segment (256B), 16 cols per pass.
    const int rj = tid >> 4;              // 0..15
    const int rl = tid & 15;              // 0..15
    #pragma unroll
    for (int it = 0; it < 8; ++it) {
        const int jl = it * 16 + rj;
        short8 vrow = *reinterpret_cast<const short8*>(&T[jl * TSTRIDE + rl * 8]);
        *reinterpret_cast<short8*>(Dmat + (size_t)(j0base + jl) * 512 + i0base + rl * 8) = vrow;
    }
}

// ---- Phase 3: barrier-free one-wave hardmin DTW, depth-2 group prefetch ---
// grid 192 x 64 threads (one wave). Lane t owns rows [8t, 8t+8).
// Step s: lane t computes column j = s - t. 576 steps in 72 groups of 8.
__global__ __launch_bounds__(64) void dtw_wave_kernel(
    const unsigned short* __restrict__ Dws, float* __restrict__ out) {
    const int z = blockIdx.x;            // 3*b + p
    const int b = z / 3;
    const int p = z - 3 * b;
    const unsigned short* Dmat = Dws + (size_t)z * 262144;   // col-major
    const int t = threadIdx.x;           // lane 0..63

    float prev[8];                        // R[8t+r, j-1]
    #pragma unroll
    for (int r = 0; r < 8; ++r) prev[r] = SDTW_BIG;
    float bot = SDTW_BIG;                 // bottom-row value after last step
    float u1s = SDTW_BIG;                 // shfl received last step

    const uint4* Dcol = reinterpret_cast<const uint4*>(Dmat) + t;  // + j*64

    uint4 cur[8], nxt[8];
    #pragma unroll
    for (int k = 0; k < 8; ++k) {         // group 0
        const int j0k = k - t;
        const int jc = j0k < 0 ? 0 : (j0k > 511 ? 511 : j0k);
        cur[k] = Dcol[(size_t)jc * 64];
    }
    #pragma unroll
    for (int k = 0; k < 8; ++k) {         // group 1
        const int j1k = 8 + k - t;
        const int jc = j1k < 0 ? 0 : (j1k > 511 ? 511 : j1k);
        nxt[k] = Dcol[(size_t)jc * 64];
    }

    for (int g = 0; g < 72; ++g) {
        const int s0 = g * 8;
        // prefetch group g+2: 16 loads in flight during 2 groups of compute
        uint4 fut[8];
        #pragma unroll
        for (int k = 0; k < 8; ++k) {
            const int jn = s0 + 16 + k - t;
            const int jc = jn < 0 ? 0 : (jn > 511 ? 511 : jn);
            fut[k] = Dcol[(size_t)jc * 64];
        }
        #pragma unroll
        for (int k = 0; k < 8; ++k) {
            const int j = s0 + k - t;
            const float recv = __shfl_up(bot, 1);
            float u0 = u1s;      // lane t-1 bottom @ s-2 = R[8t-1, j-1]
            float u1 = recv;     // lane t-1 bottom @ s-1 = R[8t-1, j]
            u1s = recv;
            if (t == 0) { u1 = SDTW_BIG; u0 = (j == 0) ? 0.0f : SDTW_BIG; }
            else if (j == 0) { u0 = SDTW_BIG; }

            if (j >= 0 && j < 512) {
                float d[8];
                d[0] = bf2f_lo(cur[k].x); d[1] = bf2f_hi(cur[k].x);
                d[2] = bf2f_lo(cur[k].y); d[3] = bf2f_hi(cur[k].y);
                d[4] = bf2f_lo(cur[k].z); d[5] = bf2f_hi(cur[k].z);
                d[6] = bf2f_lo(cur[k].w); d[7] = bf2f_hi(cur[k].w);
                // off-chain: e_r = fmin(diag_r, left_r)
                float e[8];
                e[0] = fminf(u0, prev[0]);
                #pragma unroll
                for (int r = 1; r < 8; ++r) e[r] = fminf(prev[r - 1], prev[r]);
                // chain: c_r = d_r + fmin(e_r, c_{r-1})  (2 dependent ops/cell)
                float c = d[0] + fminf(e[0], u1);
                float nv[8]; nv[0] = c;
                #pragma unroll
                for (int r = 1; r < 8; ++r) { c = d[r] + fminf(e[r], c); nv[r] = c; }
                #pragma unroll
                for (int r = 0; r < 8; ++r) prev[r] = nv[r];
                bot = c;          // R[8t+7, j]
            }
        }
        #pragma unroll
        for (int k = 0; k < 8; ++k) { cur[k] = nxt[k]; nxt[k] = fut[k]; }
    }

    if (t == 63) {                // bot == R[511,511]
        const float coef = (p == 0) ? 1.0f : -0.5f;
        atomicAdd(&out[b], coef * bot);
    }
}

extern "C" void kernel_launch(void* const* d_in, const int* in_sizes, int n_in,
                              void* d_out, int out_size, void* d_ws, size_t ws_size,
                              hipStream_t stream) {
    const float* x = (const float*)d_in[0];
    const float* y = (const float*)d_in[1];
    float* out = (float*)d_out;
    char* ws = (char*)d_ws;

    // ws layout (bytes):
    //   [0, 100663296)              D bf16, 192 matrices x 262144 elems (col-major)
    //   [100663296, 117440512)      xb bf16
    //   [117440512, 134217728)      yb bf16
    //   [134217728, 134348800)      nx fp32
    //   [134348800, 134479872)      ny fp32
    unsigned short* Dws = (unsigned short*)ws;
    unsigned short* xb  = (unsigned short*)(ws + 100663296);
    unsigned short* yb  = (unsigned short*)(ws + 117440512);
    float* nx = (float*)(ws + 134217728);
    float* ny = (float*)(ws + 134348800);

    hipMemsetAsync(d_out, 0, 64 * sizeof(float), stream);
    convert_norm_kernel<<<dim3(8192, 2), 256, 0, stream>>>(x, y, xb, yb, nx, ny);
    gemm_lds_kernel<<<dim3(4, 4, 192), 256, 0, stream>>>(xb, yb, nx, ny, Dws);
    dtw_wave_kernel<<<192, 64, 0, stream>>>(Dws, out);
}

// Round 7
// 237.556 us; speedup vs baseline: 1.2847x; 1.2847x over previous
//
#include <hip/hip_runtime.h>
#include <hip/hip_bf16.h>

// DTWLoss: out[b] = softDTW(sqdist(x,y)) - 0.5*(softDTW(sqdist(x,x)) + softDTW(sqdist(y,y)))
// B=64, N=M=512, F=256, gamma=0.1, BIG=1e8. Output: 64 fp32.
//
// Phase 1: convert x,y to bf16 + fp32 row norms.
// Phase 2: EXACT round-5 gemm (known 79us): 128x128 tile, LDS dbuf chunk K=32,
//          LDA=40, separate static Ab/Bb arrays, z=p*64+b, scattered ushort4
//          epilogue. (Round-6's bundled changes regressed to 149us despite
//          better counters — reverted wholesale.)
// Phase 3: barrier-free wavefront DTW (hardmin), ONE WAVE per matrix, lane t
//          owns rows [8t,8t+8), depth-2 group-8 prefetch. KEY FIX:
//          __launch_bounds__(64,1) — round-4's (64) default let the allocator
//          target 8 waves/EU, capping VGPRs at ~20 and SINKING the prefetch
//          loads to use sites (MLP=1 -> 191us). With min-waves=1 the 24 uint4
//          payload regs stay live and loads stay in flight.

#define SDTW_BIG   1e8f
#define LDA 40   // LDS row stride in shorts (32 + 8 pad)

typedef __attribute__((ext_vector_type(8))) short short8;   // 8 bf16
typedef __attribute__((ext_vector_type(4))) float floatx4;  // mfma acc

__device__ __forceinline__ unsigned short f2bf(float f) {
    __hip_bfloat16 h = __float2bfloat16(f);
    return *reinterpret_cast<unsigned short*>(&h);
}
__device__ __forceinline__ float bf2f_lo(unsigned int u) {
    return __uint_as_float(u << 16);
}
__device__ __forceinline__ float bf2f_hi(unsigned int u) {
    return __uint_as_float(u & 0xFFFF0000u);
}

// ---- Phase 1: fp32 -> bf16 + row sum-of-squares (fp32) --------------------
__global__ __launch_bounds__(256) void convert_norm_kernel(
    const float* __restrict__ x, const float* __restrict__ y,
    unsigned short* __restrict__ xb, unsigned short* __restrict__ yb,
    float* __restrict__ nx, float* __restrict__ ny) {
    const float* src = blockIdx.y ? y : x;
    unsigned short* dst = blockIdx.y ? yb : xb;
    float* nrm = blockIdx.y ? ny : nx;
    const int wave = threadIdx.x >> 6;
    const int lane = threadIdx.x & 63;
    const int row  = blockIdx.x * 4 + wave;          // 0..32767
    const float4 v = reinterpret_cast<const float4*>(src + (size_t)row * 256)[lane];
    float ss = v.x * v.x + v.y * v.y + v.z * v.z + v.w * v.w;
    ushort4 u;
    u.x = f2bf(v.x); u.y = f2bf(v.y); u.z = f2bf(v.z); u.w = f2bf(v.w);
    reinterpret_cast<ushort4*>(dst + (size_t)row * 256)[lane] = u;
    #pragma unroll
    for (int o = 32; o; o >>= 1) ss += __shfl_down(ss, o);
    if (lane == 0) nrm[row] = ss;
}

// ---- Phase 2: D = nA[i] + nB[j] - 2*A.B^T, bf16 col-major, LDS dbuf -------
// grid (4, 4, 192) x 256 threads. 128x128 tile/block; wave (wr,wc) does the
// 64x64 quadrant via 4x4 MFMA tiles. K = 8 chunks x 32.  [round-5 exact]
__global__ __launch_bounds__(256) void gemm_lds_kernel(
    const unsigned short* __restrict__ xb, const unsigned short* __restrict__ yb,
    const float* __restrict__ nx, const float* __restrict__ ny,
    unsigned short* __restrict__ Dws) {
    __shared__ short Ab[2][128 * LDA];
    __shared__ short Bb[2][128 * LDA];

    const int z = blockIdx.z;            // p*64 + b
    const int p = z >> 6;
    const int b = z & 63;
    const unsigned short* A  = (p == 2) ? yb : xb;
    const unsigned short* Bm = (p == 1) ? xb : yb;
    const float* nA = (p == 2) ? ny : nx;
    const float* nB = (p == 1) ? nx : ny;
    A  += (size_t)b * (512 * 256);
    Bm += (size_t)b * (512 * 256);
    nA += b * 512;
    nB += b * 512;
    unsigned short* Dmat = Dws + (size_t)z * (512 * 512);

    const int tid  = threadIdx.x;
    const int wave = tid >> 6;
    const int lane = tid & 63;
    const int quad = lane >> 4;
    const int l16  = lane & 15;
    const int wr = wave >> 1, wc = wave & 1;
    const int i0base = blockIdx.x * 128;
    const int j0base = blockIdx.y * 128;

    const int srow = tid >> 2;
    const int sq   = tid & 3;
    const short8* gA0 = reinterpret_cast<const short8*>(A  + (size_t)(i0base + srow)      * 256 + sq * 8);
    const short8* gA1 = reinterpret_cast<const short8*>(A  + (size_t)(i0base + srow + 64) * 256 + sq * 8);
    const short8* gB0 = reinterpret_cast<const short8*>(Bm + (size_t)(j0base + srow)      * 256 + sq * 8);
    const short8* gB1 = reinterpret_cast<const short8*>(Bm + (size_t)(j0base + srow + 64) * 256 + sq * 8);
    const int lO0 = srow * LDA + sq * 8;
    const int lO1 = (srow + 64) * LDA + sq * 8;

    {
        short8 ra0 = gA0[0], ra1 = gA1[0], rb0 = gB0[0], rb1 = gB1[0];
        *reinterpret_cast<short8*>(&Ab[0][lO0]) = ra0;
        *reinterpret_cast<short8*>(&Ab[0][lO1]) = ra1;
        *reinterpret_cast<short8*>(&Bb[0][lO0]) = rb0;
        *reinterpret_cast<short8*>(&Bb[0][lO1]) = rb1;
    }
    __syncthreads();

    floatx4 acc[4][4];
    #pragma unroll
    for (int mt = 0; mt < 4; ++mt)
        #pragma unroll
        for (int nt = 0; nt < 4; ++nt) acc[mt][nt] = (floatx4){0.f, 0.f, 0.f, 0.f};

    #pragma unroll
    for (int c = 0; c < 8; ++c) {
        const int cb = c & 1;
        short8 na0, na1, nb0, nb1;
        if (c < 7) {
            na0 = gA0[(c + 1) * 4]; na1 = gA1[(c + 1) * 4];
            nb0 = gB0[(c + 1) * 4]; nb1 = gB1[(c + 1) * 4];
        }
        short8 af[4], bfr[4];
        #pragma unroll
        for (int mt = 0; mt < 4; ++mt)
            af[mt] = *reinterpret_cast<const short8*>(&Ab[cb][(wr * 64 + mt * 16 + l16) * LDA + quad * 8]);
        #pragma unroll
        for (int nt = 0; nt < 4; ++nt)
            bfr[nt] = *reinterpret_cast<const short8*>(&Bb[cb][(wc * 64 + nt * 16 + l16) * LDA + quad * 8]);
        #pragma unroll
        for (int mt = 0; mt < 4; ++mt)
            #pragma unroll
            for (int nt = 0; nt < 4; ++nt)
                acc[mt][nt] = __builtin_amdgcn_mfma_f32_16x16x32_bf16(af[mt], bfr[nt], acc[mt][nt], 0, 0, 0);
        if (c < 7) {
            *reinterpret_cast<short8*>(&Ab[1 - cb][lO0]) = na0;
            *reinterpret_cast<short8*>(&Ab[1 - cb][lO1]) = na1;
            *reinterpret_cast<short8*>(&Bb[1 - cb][lO0]) = nb0;
            *reinterpret_cast<short8*>(&Bb[1 - cb][lO1]) = nb1;
            __syncthreads();
        }
    }

    // Epilogue: C/D layout col=lane&15, row=quad*4+reg (m89-verified).
    #pragma unroll
    for (int mt = 0; mt < 4; ++mt) {
        const int ibase = i0base + wr * 64 + mt * 16 + quad * 4;
        const float4 nv = *reinterpret_cast<const float4*>(nA + ibase);
        #pragma unroll
        for (int nt = 0; nt < 4; ++nt) {
            const int j = j0base + wc * 64 + nt * 16 + l16;
            const float y2 = nB[j];
            ushort4 pk;
            pk.x = f2bf(nv.x + y2 - 2.0f * acc[mt][nt][0]);
            pk.y = f2bf(nv.y + y2 - 2.0f * acc[mt][nt][1]);
            pk.z = f2bf(nv.z + y2 - 2.0f * acc[mt][nt][2]);
            pk.w = f2bf(nv.w + y2 - 2.0f * acc[mt][nt][3]);
            *reinterpret_cast<ushort4*>(Dmat + (size_t)j * 512 + ibase) = pk;
        }
    }
}

// ---- Phase 3: barrier-free one-wave hardmin DTW, depth-2 group prefetch ---
// grid 192 x 64 threads (one wave). Lane t owns rows [8t, 8t+8).
// __launch_bounds__(64, 1): give the allocator the full VGPR budget so the
// 24 uint4 prefetch payload stays live (round-4: VGPR=20 => loads sunk).
__global__ __launch_bounds__(64, 1) void dtw_wave_kernel(
    const unsigned short* __restrict__ Dws, float* __restrict__ out) {
    const int z = blockIdx.x;            // p*64 + b
    const int p = z >> 6;
    const int b = z & 63;
    const unsigned short* Dmat = Dws + (size_t)z * 262144;   // col-major
    const int t = threadIdx.x;           // lane 0..63

    float prev[8];                        // R[8t+r, j-1]
    #pragma unroll
    for (int r = 0; r < 8; ++r) prev[r] = SDTW_BIG;
    float bot = SDTW_BIG;                 // bottom-row value after last step
    float u1s = SDTW_BIG;                 // shfl received last step

    const uint4* Dcol = reinterpret_cast<const uint4*>(Dmat) + t;  // + j*64

    uint4 cur[8], nxt[8];
    #pragma unroll
    for (int k = 0; k < 8; ++k) {         // group 0
        const int j0k = k - t;
        const int jc = j0k < 0 ? 0 : (j0k > 511 ? 511 : j0k);
        cur[k] = Dcol[(size_t)jc * 64];
    }
    #pragma unroll
    for (int k = 0; k < 8; ++k) {         // group 1
        const int j1k = 8 + k - t;
        const int jc = j1k < 0 ? 0 : (j1k > 511 ? 511 : j1k);
        nxt[k] = Dcol[(size_t)jc * 64];
    }

    for (int g = 0; g < 72; ++g) {
        const int s0 = g * 8;
        // prefetch group g+2: 16 loads in flight during 2 groups of compute
        uint4 fut[8];
        #pragma unroll
        for (int k = 0; k < 8; ++k) {
            const int jn = s0 + 16 + k - t;
            const int jc = jn < 0 ? 0 : (jn > 511 ? 511 : jn);
            fut[k] = Dcol[(size_t)jc * 64];
        }
        #pragma unroll
        for (int k = 0; k < 8; ++k) {
            const int j = s0 + k - t;
            const float recv = __shfl_up(bot, 1);
            float u0 = u1s;      // lane t-1 bottom @ s-2 = R[8t-1, j-1]
            float u1 = recv;     // lane t-1 bottom @ s-1 = R[8t-1, j]
            u1s = recv;
            if (t == 0) { u1 = SDTW_BIG; u0 = (j == 0) ? 0.0f : SDTW_BIG; }
            else if (j == 0) { u0 = SDTW_BIG; }

            if (j >= 0 && j < 512) {
                float d[8];
                d[0] = bf2f_lo(cur[k].x); d[1] = bf2f_hi(cur[k].x);
                d[2] = bf2f_lo(cur[k].y); d[3] = bf2f_hi(cur[k].y);
                d[4] = bf2f_lo(cur[k].z); d[5] = bf2f_hi(cur[k].z);
                d[6] = bf2f_lo(cur[k].w); d[7] = bf2f_hi(cur[k].w);
                // off-chain: e_r = fmin(diag_r, left_r)
                float e[8];
                e[0] = fminf(u0, prev[0]);
                #pragma unroll
                for (int r = 1; r < 8; ++r) e[r] = fminf(prev[r - 1], prev[r]);
                // chain: c_r = d_r + fmin(e_r, c_{r-1})  (2 dependent ops/cell)
                float c = d[0] + fminf(e[0], u1);
                float nv[8]; nv[0] = c;
                #pragma unroll
                for (int r = 1; r < 8; ++r) { c = d[r] + fminf(e[r], c); nv[r] = c; }
                #pragma unroll
                for (int r = 0; r < 8; ++r) prev[r] = nv[r];
                bot = c;          // R[8t+7, j]
            }
        }
        #pragma unroll
        for (int k = 0; k < 8; ++k) { cur[k] = nxt[k]; nxt[k] = fut[k]; }
    }

    if (t == 63) {                // bot == R[511,511]
        const float coef = (p == 0) ? 1.0f : -0.5f;
        atomicAdd(&out[b], coef * bot);
    }
}

extern "C" void kernel_launch(void* const* d_in, const int* in_sizes, int n_in,
                              void* d_out, int out_size, void* d_ws, size_t ws_size,
                              hipStream_t stream) {
    const float* x = (const float*)d_in[0];
    const float* y = (const float*)d_in[1];
    float* out = (float*)d_out;
    char* ws = (char*)d_ws;

    // ws layout (bytes):
    //   [0, 100663296)              D bf16, 192 matrices x 262144 elems (col-major)
    //   [100663296, 117440512)      xb bf16
    //   [117440512, 134217728)      yb bf16
    //   [134217728, 134348800)      nx fp32
    //   [134348800, 134479872)      ny fp32
    unsigned short* Dws = (unsigned short*)ws;
    unsigned short* xb  = (unsigned short*)(ws + 100663296);
    unsigned short* yb  = (unsigned short*)(ws + 117440512);
    float* nx = (float*)(ws + 134217728);
    float* ny = (float*)(ws + 134348800);

    hipMemsetAsync(d_out, 0, 64 * sizeof(float), stream);
    convert_norm_kernel<<<dim3(8192, 2), 256, 0, stream>>>(x, y, xb, yb, nx, ny);
    gemm_lds_kernel<<<dim3(4, 4, 192), 256, 0, stream>>>(xb, yb, nx, ny, Dws);
    dtw_wave_kernel<<<192, 64, 0, stream>>>(Dws, out);
}